// Round 3
// baseline (841.593 us; speedup 1.0000x reference)
//
#include <hip/hip_runtime.h>

// Problem constants (match reference)
static constexpr int DIM = 128;
static constexpr int N = DIM * DIM * DIM;        // 2,097,152 voxels
static constexpr int ITERS = 20;
static constexpr float EPS = 1e-6f;

// Gaussian(sigma=1, radius=3) normalized weights
#define W0 0.39905028f
#define W1 0.24203624f
#define W2 0.05400559f
#define W3 0.00443305f

__device__ __forceinline__ int clamp_i(int v, int lo, int hi) {
    return min(max(v, lo), hi);
}

// ---------------------------------------------------------------------------
// Prologue: gradient of the fixed image (iteration-invariant).
// gfix[0*N]=d/dz, gfix[1*N]=d/dy, gfix[2*N]=d/dx — same one-sided/central
// formulas as the in-loop code, so results are bitwise identical.
// One float4 per thread; x-halo fetched via lane shuffles (lane i-1 holds
// fix[idx-1] in .w). Lane 0/31 shuffle garbage only reaches the unused
// select arm (xi==0 / xi==127 one-sided formulas).
// ---------------------------------------------------------------------------
__global__ __launch_bounds__(256) void grad_fix_kernel(const float* __restrict__ fix,
                                                       float* __restrict__ gfix) {
    int g = blockIdx.x * 256 + threadIdx.x;   // 0 .. N/4-1
    int idx = g << 2;
    int z = idx >> 14;
    int gy = (idx >> 7) & 127;
    int xb = idx & 127;

    float4 fc4 = *(const float4*)(fix + idx);

    int iyp = (gy < 127) ? idx + 128   : idx;
    int iym = (gy > 0)   ? idx - 128   : idx;
    int izp = (z < 127)  ? idx + 16384 : idx;
    int izm = (z > 0)    ? idx - 16384 : idx;

    float4 fyp = *(const float4*)(fix + iyp), fym = *(const float4*)(fix + iym);
    float4 fzp = *(const float4*)(fix + izp), fzm = *(const float4*)(fix + izm);

    float fl = __shfl_up(fc4.w, 1);    // fix[idx-1] (garbage at xb==0, unused)
    float fr = __shfl_down(fc4.x, 1);  // fix[idx+4] (garbage at xb==124, unused)

    float fcv[4]  = {fc4.x, fc4.y, fc4.z, fc4.w};
    float fypv[4] = {fyp.x, fyp.y, fyp.z, fyp.w};
    float fymv[4] = {fym.x, fym.y, fym.z, fym.w};
    float fzpv[4] = {fzp.x, fzp.y, fzp.z, fzp.w};
    float fzmv[4] = {fzm.x, fzm.y, fzm.z, fzm.w};

    float gzv[4], gyv[4], gxv[4];
#pragma unroll
    for (int i = 0; i < 4; ++i) {
        float fc = fcv[i];
        gzv[i] = (z == 0)   ? (fzpv[i] - fc)
               : (z == 127) ? (fc - fzmv[i])
               : 0.5f * (fzpv[i] - fzmv[i]);
        gyv[i] = (gy == 0)   ? (fypv[i] - fc)
               : (gy == 127) ? (fc - fymv[i])
               : 0.5f * (fypv[i] - fymv[i]);
        float fleft  = (i == 0) ? fl : fcv[i - 1];
        float fright = (i == 3) ? fr : fcv[i + 1];
        int xi = xb + i;
        gxv[i] = (xi == 0)   ? (fright - fc)
               : (xi == 127) ? (fc - fleft)
               : 0.5f * (fright - fleft);
    }
    *(float4*)(gfix + idx)         = make_float4(gzv[0], gzv[1], gzv[2], gzv[3]);
    *(float4*)(gfix + N + idx)     = make_float4(gyv[0], gyv[1], gyv[2], gyv[3]);
    *(float4*)(gfix + 2 * N + idx) = make_float4(gxv[0], gxv[1], gxv[2], gxv[3]);
}

// ---------------------------------------------------------------------------
// Fused forces (ALL 3 channels, once per voxel) + x-blur + y-blur.
// One block per (z-plane, 16-row y-strip). Forces computed in registers for
// the 22-row halo strip; x-blur done IN REGISTERS via lane shuffles.
// Only the x-blurred value is written to LDS (1 barrier instead of 3).
// Stage C: y-blur LDS -> global u2. u never materialized.
// LDS = 3*22*132*4 = 34848 B -> 4 blocks/CU (LDS limit).
//
// R3: stage-A VMEM 17 -> 12 ops/item:
//   - x-halo scalars (wl/wr/fl/fr) via lane shuffles from the center float4
//     (lane i-1's .w == [idx-1]); lane-0/31 garbage only feeds the unused
//     one-sided select arms.
//   - GFIX variant: fixed-image gradient precomputed once (grad_fix_kernel),
//     loaded as 3 float4 instead of 4 neighbor float4 + gradient math.
//
// XCD swizzle (T1): decode so XCD k owns y-strip k for ALL 128 z:
//   z = b>>3, y0 = (b&7)*16.  (~-10% measured in R1.)
// ---------------------------------------------------------------------------
#define ROWS 22            // 16 + 2*3 halo
#define SSTR 132           // padded row stride (floats), 16B-aligned
#define SC(c, r) ((((c) * ROWS) + (r)) * SSTR)

template <bool FIRST, bool GFIX>
__global__ __launch_bounds__(256, 4) void forces_xy_kernel(const float* __restrict__ wpd,
                                                           const float* __restrict__ fix,
                                                           const float* __restrict__ gfix,
                                                           const float* __restrict__ vf,
                                                           float* __restrict__ u2) {
    int b = blockIdx.x;          // 1024 blocks
    int z  = b >> 3;             // XCD-swizzled: all z of one y-strip per XCD
    int y0 = (b & 7) << 4;       // 0,16,...,112  (strip id == XCD id)

    __shared__ float S[3 * ROWS * SSTR];

    // ---- Stage A+B: forces (one eval/voxel, all channels) + x-blur -> S
    // 704 items over 256 threads; 704 = 11*64 so every executing wave is
    // fully active. The gy-guard is uniform per 32-lane half-wave (lanes
    // 0..31 share one row, 32..63 the next), and all shuffles that cross
    // the half boundary land only in unused lanes (x4==0/31 select arms).
    for (int e = threadIdx.x; e < ROWS * 32; e += 256) {
        int x4 = e & 31;
        int r  = e >> 5;
        int gy = y0 + r - 3;
        float4 rz = make_float4(0, 0, 0, 0);
        float4 ry = make_float4(0, 0, 0, 0);
        float4 rx = make_float4(0, 0, 0, 0);
        if (gy >= 0 && gy < 128) {
            int idx = (z << 14) + (gy << 7) + (x4 << 2);
            int xb = x4 << 2;

            float4 wc4 = *(const float4*)(wpd + idx);
            float4 fc4 = *(const float4*)(fix + idx);

            int iyp = (gy < 127) ? idx + 128   : idx;
            int iym = (gy > 0)   ? idx - 128   : idx;
            int izp = (z < 127)  ? idx + 16384 : idx;
            int izm = (z > 0)    ? idx - 16384 : idx;

            float4 wyp = *(const float4*)(wpd + iyp), wym = *(const float4*)(wpd + iym);
            float4 wzp = *(const float4*)(wpd + izp), wzm = *(const float4*)(wpd + izm);

            // x-halo via shuffle (replaces 2 scalar loads)
            float wl = __shfl_up(wc4.w, 1);
            float wr = __shfl_down(wc4.x, 1);

            float wcv[4] = {wc4.x, wc4.y, wc4.z, wc4.w};
            float fcv[4] = {fc4.x, fc4.y, fc4.z, fc4.w};
            float wypv[4] = {wyp.x, wyp.y, wyp.z, wyp.w};
            float wymv[4] = {wym.x, wym.y, wym.z, wym.w};
            float wzpv[4] = {wzp.x, wzp.y, wzp.z, wzp.w};
            float wzmv[4] = {wzm.x, wzm.y, wzm.z, wzm.w};

            float gfzv[4], gfyv[4], gfxv[4];
            if (GFIX) {
                float4 gz4 = *(const float4*)(gfix + idx);
                float4 gy4 = *(const float4*)(gfix + N + idx);
                float4 gx4 = *(const float4*)(gfix + 2 * N + idx);
                gfzv[0] = gz4.x; gfzv[1] = gz4.y; gfzv[2] = gz4.z; gfzv[3] = gz4.w;
                gfyv[0] = gy4.x; gfyv[1] = gy4.y; gfyv[2] = gy4.z; gfyv[3] = gy4.w;
                gfxv[0] = gx4.x; gfxv[1] = gx4.y; gfxv[2] = gx4.z; gfxv[3] = gx4.w;
            } else {
                float4 fyp = *(const float4*)(fix + iyp), fym = *(const float4*)(fix + iym);
                float4 fzp = *(const float4*)(fix + izp), fzm = *(const float4*)(fix + izm);
                float fl = __shfl_up(fc4.w, 1);
                float fr = __shfl_down(fc4.x, 1);
                float fypv[4] = {fyp.x, fyp.y, fyp.z, fyp.w};
                float fymv[4] = {fym.x, fym.y, fym.z, fym.w};
                float fzpv[4] = {fzp.x, fzp.y, fzp.z, fzp.w};
                float fzmv[4] = {fzm.x, fzm.y, fzm.z, fzm.w};
#pragma unroll
                for (int i = 0; i < 4; ++i) {
                    float fc = fcv[i];
                    gfzv[i] = (z == 0)   ? (fzpv[i] - fc)
                            : (z == 127) ? (fc - fzmv[i])
                            : 0.5f * (fzpv[i] - fzmv[i]);
                    gfyv[i] = (gy == 0)   ? (fypv[i] - fc)
                            : (gy == 127) ? (fc - fymv[i])
                            : 0.5f * (fypv[i] - fymv[i]);
                    float fleft  = (i == 0) ? fl : fcv[i - 1];
                    float fright = (i == 3) ? fr : fcv[i + 1];
                    int xi = xb + i;
                    gfxv[i] = (xi == 0)   ? (fright - fc)
                            : (xi == 127) ? (fc - fleft)
                            : 0.5f * (fright - fleft);
                }
            }

            float4 vz4 = FIRST ? make_float4(0, 0, 0, 0) : *(const float4*)(vf + idx);
            float4 vy4 = FIRST ? make_float4(0, 0, 0, 0) : *(const float4*)(vf + N + idx);
            float4 vx4 = FIRST ? make_float4(0, 0, 0, 0) : *(const float4*)(vf + 2 * N + idx);
            float vzv[4] = {vz4.x, vz4.y, vz4.z, vz4.w};
            float vyv[4] = {vy4.x, vy4.y, vy4.z, vy4.w};
            float vxv[4] = {vx4.x, vx4.y, vx4.z, vx4.w};

            float ozv[4], oyv[4], oxv[4];
#pragma unroll
            for (int i = 0; i < 4; ++i) {
                float wc = wcv[i], fc = fcv[i];
                float diff = wc - fc;

                float gwz = (z == 0)   ? (wzpv[i] - wc)
                          : (z == 127) ? (wc - wzmv[i])
                          : 0.5f * (wzpv[i] - wzmv[i]);
                float grz = 0.5f * (gwz + gfzv[i]);

                float gwy = (gy == 0)   ? (wypv[i] - wc)
                          : (gy == 127) ? (wc - wymv[i])
                          : 0.5f * (wypv[i] - wymv[i]);
                float gry = 0.5f * (gwy + gfyv[i]);

                float wleft  = (i == 0) ? wl : wcv[i - 1];
                float wright = (i == 3) ? wr : wcv[i + 1];
                int xi = xb + i;
                float gwx = (xi == 0)   ? (wright - wc)
                          : (xi == 127) ? (wc - wleft)
                          : 0.5f * (wright - wleft);
                float grx = 0.5f * (gwx + gfxv[i]);

                float denom = grz * grz + gry * gry + grx * grx + diff * diff;
                float s = (denom > EPS) ? (diff / denom) : 0.0f;
                ozv[i] = vzv[i] + s * grz;
                oyv[i] = vyv[i] + s * gry;
                oxv[i] = vxv[i] + s * grx;
            }
            rz = make_float4(ozv[0], ozv[1], ozv[2], ozv[3]);
            ry = make_float4(oyv[0], oyv[1], oyv[2], oyv[3]);
            rx = make_float4(oxv[0], oxv[1], oxv[2], oxv[3]);
        }

        // x-blur in registers via lane shuffles (all 64 lanes of each
        // executing wave are active here; OOB rows carry zeros = zero-pad).
        float4 vch[3] = {rz, ry, rx};
#pragma unroll
        for (int c = 0; c < 3; ++c) {
            float4 v0 = vch[c];
            float4 m1, p1;
            m1.x = __shfl_up(v0.x, 1);  m1.y = __shfl_up(v0.y, 1);
            m1.z = __shfl_up(v0.z, 1);  m1.w = __shfl_up(v0.w, 1);
            p1.x = __shfl_down(v0.x, 1); p1.y = __shfl_down(v0.y, 1);
            p1.z = __shfl_down(v0.z, 1); p1.w = __shfl_down(v0.w, 1);
            if (x4 == 0)  m1 = make_float4(0, 0, 0, 0);
            if (x4 == 31) p1 = make_float4(0, 0, 0, 0);
            float w[12] = {m1.x, m1.y, m1.z, m1.w,
                           v0.x, v0.y, v0.z, v0.w,
                           p1.x, p1.y, p1.z, p1.w};
            float o[4];
#pragma unroll
            for (int i = 0; i < 4; ++i) {
                o[i] = W3 * (w[i + 1] + w[i + 7]) + W2 * (w[i + 2] + w[i + 6])
                     + W1 * (w[i + 3] + w[i + 5]) + W0 * w[i + 4];
            }
            *(float4*)(S + SC(c, r) + (x4 << 2)) = make_float4(o[0], o[1], o[2], o[3]);
        }
    }
    __syncthreads();

    // ---- Stage C: y-blur S -> global u2 (16 rows x 32 float4 x 3 ch)
    for (int e = threadIdx.x; e < 16 * 32 * 3; e += 256) {
        int x4 = e & 31;
        int t2 = e >> 5;
        int y  = t2 & 15;
        int c  = t2 >> 4;
        const float* base = S + SC(c, y) + (x4 << 2);   // rows y..y+6 (halo offset)
        float4 v0 = *(const float4*)(base);
        float4 v1 = *(const float4*)(base + 1 * SSTR);
        float4 v2 = *(const float4*)(base + 2 * SSTR);
        float4 v3 = *(const float4*)(base + 3 * SSTR);
        float4 v4 = *(const float4*)(base + 4 * SSTR);
        float4 v5 = *(const float4*)(base + 5 * SSTR);
        float4 v6 = *(const float4*)(base + 6 * SSTR);
        float4 acc;
        acc.x = W3 * (v0.x + v6.x) + W2 * (v1.x + v5.x) + W1 * (v2.x + v4.x) + W0 * v3.x;
        acc.y = W3 * (v0.y + v6.y) + W2 * (v1.y + v5.y) + W1 * (v2.y + v4.y) + W0 * v3.y;
        acc.z = W3 * (v0.z + v6.z) + W2 * (v1.z + v5.z) + W1 * (v2.z + v4.z) + W0 * v3.z;
        acc.w = W3 * (v0.w + v6.w) + W2 * (v1.w + v5.w) + W1 * (v2.w + v4.w) + W0 * v3.w;
        *(float4*)(u2 + (size_t)c * N + ((size_t)z << 14) + ((y0 + y) << 7) + (x4 << 2)) = acc;
    }
}

// ---------------------------------------------------------------------------
// Fused z-blur + (next iteration's) trilinear warp (proven R9 version).
// One thread owns an (x,y) column x 8-z chunk for ALL 3 channels.
//
// XCD swizzle (T1), y-strip-ALIGNED with forces_xy_kernel: XCD k gets
// y-rows [16k,16k+16) across all 16 z-chunks (bijective remap).
// ---------------------------------------------------------------------------
template <bool DO_WARP>
__global__ __launch_bounds__(256, 4) void zblur_warp_kernel(const float* __restrict__ u2,
                                                            const float* __restrict__ mov,
                                                            float* __restrict__ vf,
                                                            float* __restrict__ warped) {
    int k  = blockIdx.x & 7;
    int j  = blockIdx.x >> 3;
    int lb = ((j & 15) << 6) + (k << 3) + (j >> 4);
    int g  = lb * 256 + threadIdx.x;          // 0 .. 262143 (bijective remap)
    int col = g & 16383;                      // (y<<7)|x
    int zc  = g >> 14;                        // 0..15
    int z0  = zc << 3;
    int x = col & 127, y = col >> 7;

    float bz[3][8];
#pragma unroll
    for (int c = 0; c < 3; ++c) {
        const float* inp = u2 + (size_t)c * N + col;
        float win[14];
#pragma unroll
        for (int i = 0; i < 14; ++i) {
            int zz = z0 - 3 + i;
            win[i] = (zz >= 0 && zz < 128) ? inp[(size_t)zz << 14] : 0.0f;
        }
#pragma unroll
        for (int k8 = 0; k8 < 8; ++k8) {
            bz[c][k8] = W3 * (win[k8] + win[k8 + 6]) + W2 * (win[k8 + 1] + win[k8 + 5])
                      + W1 * (win[k8 + 2] + win[k8 + 4]) + W0 * win[k8 + 3];
        }
        float* outp = vf + (size_t)c * N + col;
#pragma unroll
        for (int k8 = 0; k8 < 8; ++k8)
            outp[(size_t)(z0 + k8) << 14] = bz[c][k8];
    }

    if (DO_WARP) {
        for (int k8 = 0; k8 < 8; ++k8) {
            int z = z0 + k8;
            float cz = (float)z + bz[0][k8];
            float cy = (float)y + bz[1][k8];
            float cx = (float)x + bz[2][k8];

            float flz = floorf(cz), fly = floorf(cy), flx = floorf(cx);
            float fz = cz - flz, fy = cy - fly, fx = cx - flx;

            int zi = (int)flz, yi = (int)fly, xi = (int)flx;
            int z0c = clamp_i(zi, 0, DIM - 1), z1c = clamp_i(zi + 1, 0, DIM - 1);
            int y0c = clamp_i(yi, 0, DIM - 1), y1c = clamp_i(yi + 1, 0, DIM - 1);
            int x0c = clamp_i(xi, 0, DIM - 1), x1c = clamp_i(xi + 1, 0, DIM - 1);

            int b00 = (z0c << 14) + (y0c << 7);
            int b01 = (z0c << 14) + (y1c << 7);
            int b10 = (z1c << 14) + (y0c << 7);
            int b11 = (z1c << 14) + (y1c << 7);

            float v000 = mov[b00 + x0c], v001 = mov[b00 + x1c];
            float v010 = mov[b01 + x0c], v011 = mov[b01 + x1c];
            float v100 = mov[b10 + x0c], v101 = mov[b10 + x1c];
            float v110 = mov[b11 + x0c], v111 = mov[b11 + x1c];

            float c00 = v000 + fx * (v001 - v000);
            float c01 = v010 + fx * (v011 - v010);
            float c10 = v100 + fx * (v101 - v100);
            float c11 = v110 + fx * (v111 - v110);
            float c0 = c00 + fy * (c01 - c00);
            float c1 = c10 + fy * (c11 - c10);
            warped[((size_t)z << 14) + col] = c0 + fz * (c1 - c0);
        }
    }
}

extern "C" void kernel_launch(void* const* d_in, const int* in_sizes, int n_in,
                              void* d_out, int out_size, void* d_ws, size_t ws_size,
                              hipStream_t stream) {
    const float* mov = (const float*)d_in[0];
    const float* fix = (const float*)d_in[1];
    float* vf = (float*)d_out;          // (3, N) — lives in d_out throughout
    float* ws = (float*)d_ws;
    float* warped = ws;                 // N floats
    float* u2     = ws + (size_t)N;     // 3N floats (xy-blurred forces)
    float* gfix   = ws + (size_t)4 * N; // 3N floats (fixed-image gradient)

    const int BLK = 256;
    const int gridFX = 128 * 8;            // 1024 (z-plane x y-strip)
    const int gridZW = (N / 8) / BLK;      // 1024

    const bool use_gfix = ws_size >= (size_t)7 * N * sizeof(float);

    if (use_gfix) {
        grad_fix_kernel<<<N / 4 / BLK, BLK, 0, stream>>>(fix, gfix);

        forces_xy_kernel<true, true><<<gridFX, BLK, 0, stream>>>(mov, fix, gfix, nullptr, u2);
        zblur_warp_kernel<true><<<gridZW, BLK, 0, stream>>>(u2, mov, vf, warped);
        for (int it = 1; it < ITERS - 1; ++it) {
            forces_xy_kernel<false, true><<<gridFX, BLK, 0, stream>>>(warped, fix, gfix, vf, u2);
            zblur_warp_kernel<true><<<gridZW, BLK, 0, stream>>>(u2, mov, vf, warped);
        }
        forces_xy_kernel<false, true><<<gridFX, BLK, 0, stream>>>(warped, fix, gfix, vf, u2);
        zblur_warp_kernel<false><<<gridZW, BLK, 0, stream>>>(u2, mov, vf, warped);
    } else {
        // Fallback: workspace too small for gfix — inline fixed-gradient path.
        forces_xy_kernel<true, false><<<gridFX, BLK, 0, stream>>>(mov, fix, nullptr, nullptr, u2);
        zblur_warp_kernel<true><<<gridZW, BLK, 0, stream>>>(u2, mov, vf, warped);
        for (int it = 1; it < ITERS - 1; ++it) {
            forces_xy_kernel<false, false><<<gridFX, BLK, 0, stream>>>(warped, fix, nullptr, vf, u2);
            zblur_warp_kernel<true><<<gridZW, BLK, 0, stream>>>(u2, mov, vf, warped);
        }
        forces_xy_kernel<false, false><<<gridFX, BLK, 0, stream>>>(warped, fix, nullptr, vf, u2);
        zblur_warp_kernel<false><<<gridZW, BLK, 0, stream>>>(u2, mov, vf, warped);
    }
}

// Round 4
// 766.551 us; speedup vs baseline: 1.0979x; 1.0979x over previous
//
#include <hip/hip_runtime.h>
#include <hip/hip_cooperative_groups.h>

namespace cg = cooperative_groups;

// Problem constants (match reference)
static constexpr int DIM = 128;
static constexpr int N = DIM * DIM * DIM;        // 2,097,152 voxels
static constexpr int ITERS = 20;
static constexpr float EPS = 1e-6f;

// Gaussian(sigma=1, radius=3) normalized weights
#define W0 0.39905028f
#define W1 0.24203624f
#define W2 0.05400559f
#define W3 0.00443305f

__device__ __forceinline__ int clamp_i(int v, int lo, int hi) {
    return min(max(v, lo), hi);
}

// ---------------------------------------------------------------------------
// Phase 1: fused forces (all 3 channels) + x-blur (register shuffles) +
// y-blur (LDS). Identical math/structure to the R2-best kernel; x-halo
// scalars come from lane shuffles (lane i-1's .w == [idx-1]; lane-0/31
// garbage only feeds the unused one-sided select arms). gfix precompute
// REVERTED (R3: +24MB footprint/iter => +9% regression).
//
// Block b -> (z = b>>3, y0 = (b&7)*16): XCD k owns y-strip k for all z
// (R1: -10% via L2 locality).
// LDS = 3*22*132*4 = 34848 B -> 4 blocks/CU; __launch_bounds__(256,4)
// caps VGPR at 128 so 1024 blocks are exactly co-resident (cooperative).
// ---------------------------------------------------------------------------
#define ROWS 22            // 16 + 2*3 halo
#define SSTR 132           // padded row stride (floats), 16B-aligned
#define SC(c, r) ((((c) * ROWS) + (r)) * SSTR)
#define LDS_FLOATS (3 * ROWS * SSTR)

__device__ __forceinline__ void forces_phase(const float* __restrict__ wpd,
                                             const float* __restrict__ fix,
                                             const float* __restrict__ vf,
                                             float* __restrict__ u2,
                                             float* S, bool first, int b) {
    int z  = b >> 3;
    int y0 = (b & 7) << 4;

    // ---- Stage A+B: forces + x-blur -> S (704 items = 11 full waves)
    for (int e = threadIdx.x; e < ROWS * 32; e += 256) {
        int x4 = e & 31;
        int r  = e >> 5;
        int gy = y0 + r - 3;
        float4 rz = make_float4(0, 0, 0, 0);
        float4 ry = make_float4(0, 0, 0, 0);
        float4 rx = make_float4(0, 0, 0, 0);
        if (gy >= 0 && gy < 128) {
            int idx = (z << 14) + (gy << 7) + (x4 << 2);
            int xb = x4 << 2;

            float4 wc4 = *(const float4*)(wpd + idx);
            float4 fc4 = *(const float4*)(fix + idx);

            int iyp = (gy < 127) ? idx + 128   : idx;
            int iym = (gy > 0)   ? idx - 128   : idx;
            int izp = (z < 127)  ? idx + 16384 : idx;
            int izm = (z > 0)    ? idx - 16384 : idx;

            float4 wyp = *(const float4*)(wpd + iyp), wym = *(const float4*)(wpd + iym);
            float4 wzp = *(const float4*)(wpd + izp), wzm = *(const float4*)(wpd + izm);
            float4 fyp = *(const float4*)(fix + iyp), fym = *(const float4*)(fix + iym);
            float4 fzp = *(const float4*)(fix + izp), fzm = *(const float4*)(fix + izm);

            // x-halo via shuffle (replaces 4 scalar loads). Lane 0/31 (and
            // cross-row lane-32 boundary) garbage only reaches the unused
            // xi==0 / xi==127 one-sided arms.
            float wl = __shfl_up(wc4.w, 1);
            float wr = __shfl_down(wc4.x, 1);
            float fl = __shfl_up(fc4.w, 1);
            float fr = __shfl_down(fc4.x, 1);

            float wcv[4] = {wc4.x, wc4.y, wc4.z, wc4.w};
            float fcv[4] = {fc4.x, fc4.y, fc4.z, fc4.w};
            float wypv[4] = {wyp.x, wyp.y, wyp.z, wyp.w};
            float wymv[4] = {wym.x, wym.y, wym.z, wym.w};
            float wzpv[4] = {wzp.x, wzp.y, wzp.z, wzp.w};
            float wzmv[4] = {wzm.x, wzm.y, wzm.z, wzm.w};
            float fypv[4] = {fyp.x, fyp.y, fyp.z, fyp.w};
            float fymv[4] = {fym.x, fym.y, fym.z, fym.w};
            float fzpv[4] = {fzp.x, fzp.y, fzp.z, fzp.w};
            float fzmv[4] = {fzm.x, fzm.y, fzm.z, fzm.w};

            float4 vz4 = first ? make_float4(0, 0, 0, 0) : *(const float4*)(vf + idx);
            float4 vy4 = first ? make_float4(0, 0, 0, 0) : *(const float4*)(vf + N + idx);
            float4 vx4 = first ? make_float4(0, 0, 0, 0) : *(const float4*)(vf + 2 * N + idx);
            float vzv[4] = {vz4.x, vz4.y, vz4.z, vz4.w};
            float vyv[4] = {vy4.x, vy4.y, vy4.z, vy4.w};
            float vxv[4] = {vx4.x, vx4.y, vx4.z, vx4.w};

            float ozv[4], oyv[4], oxv[4];
#pragma unroll
            for (int i = 0; i < 4; ++i) {
                float wc = wcv[i], fc = fcv[i];
                float diff = wc - fc;

                float gwz = (z == 0)   ? (wzpv[i] - wc)
                          : (z == 127) ? (wc - wzmv[i])
                          : 0.5f * (wzpv[i] - wzmv[i]);
                float gfz = (z == 0)   ? (fzpv[i] - fc)
                          : (z == 127) ? (fc - fzmv[i])
                          : 0.5f * (fzpv[i] - fzmv[i]);
                float grz = 0.5f * (gwz + gfz);

                float gwy = (gy == 0)   ? (wypv[i] - wc)
                          : (gy == 127) ? (wc - wymv[i])
                          : 0.5f * (wypv[i] - wymv[i]);
                float gfy = (gy == 0)   ? (fypv[i] - fc)
                          : (gy == 127) ? (fc - fymv[i])
                          : 0.5f * (fypv[i] - fymv[i]);
                float gry = 0.5f * (gwy + gfy);

                float wleft  = (i == 0) ? wl : wcv[i - 1];
                float wright = (i == 3) ? wr : wcv[i + 1];
                float fleft  = (i == 0) ? fl : fcv[i - 1];
                float fright = (i == 3) ? fr : fcv[i + 1];
                int xi = xb + i;
                float gwx = (xi == 0)   ? (wright - wc)
                          : (xi == 127) ? (wc - wleft)
                          : 0.5f * (wright - wleft);
                float gfx = (xi == 0)   ? (fright - fc)
                          : (xi == 127) ? (fc - fleft)
                          : 0.5f * (fright - fleft);
                float grx = 0.5f * (gwx + gfx);

                float denom = grz * grz + gry * gry + grx * grx + diff * diff;
                float s = (denom > EPS) ? (diff / denom) : 0.0f;
                ozv[i] = vzv[i] + s * grz;
                oyv[i] = vyv[i] + s * gry;
                oxv[i] = vxv[i] + s * grx;
            }
            rz = make_float4(ozv[0], ozv[1], ozv[2], ozv[3]);
            ry = make_float4(oyv[0], oyv[1], oyv[2], oyv[3]);
            rx = make_float4(oxv[0], oxv[1], oxv[2], oxv[3]);
        }

        // x-blur in registers via lane shuffles (all 64 lanes active here;
        // OOB rows carry zeros = zero-pad).
        float4 vch[3] = {rz, ry, rx};
#pragma unroll
        for (int c = 0; c < 3; ++c) {
            float4 v0 = vch[c];
            float4 m1, p1;
            m1.x = __shfl_up(v0.x, 1);  m1.y = __shfl_up(v0.y, 1);
            m1.z = __shfl_up(v0.z, 1);  m1.w = __shfl_up(v0.w, 1);
            p1.x = __shfl_down(v0.x, 1); p1.y = __shfl_down(v0.y, 1);
            p1.z = __shfl_down(v0.z, 1); p1.w = __shfl_down(v0.w, 1);
            if (x4 == 0)  m1 = make_float4(0, 0, 0, 0);
            if (x4 == 31) p1 = make_float4(0, 0, 0, 0);
            float w[12] = {m1.x, m1.y, m1.z, m1.w,
                           v0.x, v0.y, v0.z, v0.w,
                           p1.x, p1.y, p1.z, p1.w};
            float o[4];
#pragma unroll
            for (int i = 0; i < 4; ++i) {
                o[i] = W3 * (w[i + 1] + w[i + 7]) + W2 * (w[i + 2] + w[i + 6])
                     + W1 * (w[i + 3] + w[i + 5]) + W0 * w[i + 4];
            }
            *(float4*)(S + SC(c, r) + (x4 << 2)) = make_float4(o[0], o[1], o[2], o[3]);
        }
    }
    __syncthreads();

    // ---- Stage C: y-blur S -> global u2 (16 rows x 32 float4 x 3 ch)
    for (int e = threadIdx.x; e < 16 * 32 * 3; e += 256) {
        int x4 = e & 31;
        int t2 = e >> 5;
        int y  = t2 & 15;
        int c  = t2 >> 4;
        const float* base = S + SC(c, y) + (x4 << 2);   // rows y..y+6 (halo offset)
        float4 v0 = *(const float4*)(base);
        float4 v1 = *(const float4*)(base + 1 * SSTR);
        float4 v2 = *(const float4*)(base + 2 * SSTR);
        float4 v3 = *(const float4*)(base + 3 * SSTR);
        float4 v4 = *(const float4*)(base + 4 * SSTR);
        float4 v5 = *(const float4*)(base + 5 * SSTR);
        float4 v6 = *(const float4*)(base + 6 * SSTR);
        float4 acc;
        acc.x = W3 * (v0.x + v6.x) + W2 * (v1.x + v5.x) + W1 * (v2.x + v4.x) + W0 * v3.x;
        acc.y = W3 * (v0.y + v6.y) + W2 * (v1.y + v5.y) + W1 * (v2.y + v4.y) + W0 * v3.y;
        acc.z = W3 * (v0.z + v6.z) + W2 * (v1.z + v5.z) + W1 * (v2.z + v4.z) + W0 * v3.z;
        acc.w = W3 * (v0.w + v6.w) + W2 * (v1.w + v5.w) + W1 * (v2.w + v4.w) + W0 * v3.w;
        *(float4*)(u2 + (size_t)c * N + ((size_t)z << 14) + ((y0 + y) << 7) + (x4 << 2)) = acc;
    }
}

// ---------------------------------------------------------------------------
// Phase 2: fused z-blur + trilinear warp (proven R9/R1 version). One thread
// owns an (x,y) column x 8-z chunk for ALL 3 channels. y-strip-aligned XCD
// remap (bijective) keeps u2 z-halo re-reads in the same XCD's L2 and
// aligns produced vf/warped strips with phase-1 consumers.
// ---------------------------------------------------------------------------
__device__ __forceinline__ void zblur_phase(const float* __restrict__ u2,
                                            const float* __restrict__ mov,
                                            float* __restrict__ vf,
                                            float* __restrict__ warped,
                                            bool do_warp, int b) {
    int k  = b & 7;
    int j  = b >> 3;
    int lb = ((j & 15) << 6) + (k << 3) + (j >> 4);
    int g  = lb * 256 + threadIdx.x;          // 0 .. 262143 (bijective remap)
    int col = g & 16383;                      // (y<<7)|x
    int zc  = g >> 14;                        // 0..15
    int z0  = zc << 3;
    int x = col & 127, y = col >> 7;

    float bz[3][8];
#pragma unroll
    for (int c = 0; c < 3; ++c) {
        const float* inp = u2 + (size_t)c * N + col;
        float win[14];
#pragma unroll
        for (int i = 0; i < 14; ++i) {
            int zz = z0 - 3 + i;
            win[i] = (zz >= 0 && zz < 128) ? inp[(size_t)zz << 14] : 0.0f;
        }
#pragma unroll
        for (int k8 = 0; k8 < 8; ++k8) {
            bz[c][k8] = W3 * (win[k8] + win[k8 + 6]) + W2 * (win[k8 + 1] + win[k8 + 5])
                      + W1 * (win[k8 + 2] + win[k8 + 4]) + W0 * win[k8 + 3];
        }
        float* outp = vf + (size_t)c * N + col;
#pragma unroll
        for (int k8 = 0; k8 < 8; ++k8)
            outp[(size_t)(z0 + k8) << 14] = bz[c][k8];
    }

    if (do_warp) {
        for (int k8 = 0; k8 < 8; ++k8) {
            int z = z0 + k8;
            float cz = (float)z + bz[0][k8];
            float cy = (float)y + bz[1][k8];
            float cx = (float)x + bz[2][k8];

            float flz = floorf(cz), fly = floorf(cy), flx = floorf(cx);
            float fz = cz - flz, fy = cy - fly, fx = cx - flx;

            int zi = (int)flz, yi = (int)fly, xi = (int)flx;
            int z0c = clamp_i(zi, 0, DIM - 1), z1c = clamp_i(zi + 1, 0, DIM - 1);
            int y0c = clamp_i(yi, 0, DIM - 1), y1c = clamp_i(yi + 1, 0, DIM - 1);
            int x0c = clamp_i(xi, 0, DIM - 1), x1c = clamp_i(xi + 1, 0, DIM - 1);

            int b00 = (z0c << 14) + (y0c << 7);
            int b01 = (z0c << 14) + (y1c << 7);
            int b10 = (z1c << 14) + (y0c << 7);
            int b11 = (z1c << 14) + (y1c << 7);

            float v000 = mov[b00 + x0c], v001 = mov[b00 + x1c];
            float v010 = mov[b01 + x0c], v011 = mov[b01 + x1c];
            float v100 = mov[b10 + x0c], v101 = mov[b10 + x1c];
            float v110 = mov[b11 + x0c], v111 = mov[b11 + x1c];

            float c00 = v000 + fx * (v001 - v000);
            float c01 = v010 + fx * (v011 - v010);
            float c10 = v100 + fx * (v101 - v100);
            float c11 = v110 + fx * (v111 - v110);
            float c0 = c00 + fy * (c01 - c00);
            float c1 = c10 + fy * (c11 - c10);
            warped[((size_t)z << 14) + col] = c0 + fz * (c1 - c0);
        }
    }
}

// ---------------------------------------------------------------------------
// R4: persistent cooperative kernel — all 20 iterations in ONE launch,
// grid.sync() between phases. Removes 39 dispatch boundaries (drain + gap
// per graph node). 1024 blocks x 256 threads = exactly 4 blocks/CU x 256 CU
// co-resident (LDS 34848 B, VGPR<=128). No __restrict__ on kernel params:
// wpd(=warped) is read in phase 1 and written in phase 2 of the same kernel.
// ---------------------------------------------------------------------------
__global__ __launch_bounds__(256, 4) void demons_persistent(const float* mov,
                                                            const float* fix,
                                                            float* vf,
                                                            float* warped,
                                                            float* u2) {
    cg::grid_group grid = cg::this_grid();
    __shared__ float S[LDS_FLOATS];
    int b = blockIdx.x;

    for (int it = 0; it < ITERS; ++it) {
        bool first = (it == 0);
        forces_phase(first ? mov : warped, fix, vf, u2, S, first, b);
        grid.sync();                                   // u2 complete
        zblur_phase(u2, mov, vf, warped, it < ITERS - 1, b);
        if (it < ITERS - 1) grid.sync();               // vf/warped complete
    }
}

// ---------------------------------------------------------------------------
// Fallback path (proven R2 structure): separate launches per phase.
// ---------------------------------------------------------------------------
template <bool FIRST>
__global__ __launch_bounds__(256, 4) void forces_xy_kernel(const float* __restrict__ wpd,
                                                           const float* __restrict__ fix,
                                                           const float* __restrict__ vf,
                                                           float* __restrict__ u2) {
    __shared__ float S[LDS_FLOATS];
    forces_phase(wpd, fix, vf, u2, S, FIRST, blockIdx.x);
}

template <bool DO_WARP>
__global__ __launch_bounds__(256, 4) void zblur_warp_kernel(const float* __restrict__ u2,
                                                            const float* __restrict__ mov,
                                                            float* __restrict__ vf,
                                                            float* __restrict__ warped) {
    zblur_phase(u2, mov, vf, warped, DO_WARP, blockIdx.x);
}

extern "C" void kernel_launch(void* const* d_in, const int* in_sizes, int n_in,
                              void* d_out, int out_size, void* d_ws, size_t ws_size,
                              hipStream_t stream) {
    const float* mov = (const float*)d_in[0];
    const float* fix = (const float*)d_in[1];
    float* vf = (float*)d_out;          // (3, N) — lives in d_out throughout
    float* ws = (float*)d_ws;
    float* warped = ws;                 // N floats
    float* u2     = ws + (size_t)N;     // 3N floats (xy-blurred forces)

    const int BLK = 256;
    const int GRID = 1024;

    // Decide cooperative support once (host-only queries; graph-capture safe).
    static int coop_ok = -1;
    if (coop_ok < 0) {
        int dev = 0;
        (void)hipGetDevice(&dev);
        int coop = 0;
        (void)hipDeviceGetAttribute(&coop, hipDeviceAttributeCooperativeLaunch, dev);
        int ncu = 0;
        (void)hipDeviceGetAttribute(&ncu, hipDeviceAttributeMultiprocessorCount, dev);
        int occ = 0;
        (void)hipOccupancyMaxActiveBlocksPerMultiprocessor(&occ, demons_persistent, BLK, 0);
        coop_ok = (coop && (long long)occ * ncu >= GRID) ? 1 : 0;
    }

    if (coop_ok) {
        void* args[] = {(void*)&mov, (void*)&fix, (void*)&vf, (void*)&warped, (void*)&u2};
        (void)hipLaunchCooperativeKernel(demons_persistent, dim3(GRID), dim3(BLK),
                                         args, 0, stream);
    } else {
        forces_xy_kernel<true><<<GRID, BLK, 0, stream>>>(mov, fix, nullptr, u2);
        zblur_warp_kernel<true><<<GRID, BLK, 0, stream>>>(u2, mov, vf, warped);
        for (int it = 1; it < ITERS - 1; ++it) {
            forces_xy_kernel<false><<<GRID, BLK, 0, stream>>>(warped, fix, vf, u2);
            zblur_warp_kernel<true><<<GRID, BLK, 0, stream>>>(u2, mov, vf, warped);
        }
        forces_xy_kernel<false><<<GRID, BLK, 0, stream>>>(warped, fix, vf, u2);
        zblur_warp_kernel<false><<<GRID, BLK, 0, stream>>>(u2, mov, vf, warped);
    }
}